// Round 1
// baseline (3092.162 us; speedup 1.0000x reference)
//
#include <hip/hip_runtime.h>
#include <hip/hip_bf16.h>

// Problem constants (from reference)
#define NN   50000
#define EE   1600000
#define INC  128
#define HH   64
#define OUTC 40
#define ALPHA 0.8f
#define LN_EPS 1e-5f

// ---------------------------------------------------------------------------
// k0: repack edge_index (int32, [2,E]) into int2[E] for single-load access
// ---------------------------------------------------------------------------
__global__ __launch_bounds__(256) void conv_edges(const int* __restrict__ ei,
                                                  int2* __restrict__ e32) {
    int i = blockIdx.x * 256 + threadIdx.x;
    if (i < EE) e32[i] = make_int2(ei[i], ei[EE + i]);
}

// ---------------------------------------------------------------------------
// k1: G = W @ W^T  (64x64, symmetric). One block.
// ---------------------------------------------------------------------------
__global__ __launch_bounds__(256) void make_G(const float* __restrict__ W,
                                              float* __restrict__ G) {
    __shared__ float Ws[64 * 64];
    for (int t = threadIdx.x; t < 64 * 64; t += 256) Ws[t] = W[t];
    __syncthreads();
    for (int t = threadIdx.x; t < 64 * 64; t += 256) {
        int i = t >> 6, j = t & 63;
        float acc = 0.f;
#pragma unroll 8
        for (int k = 0; k < 64; ++k) acc += Ws[i * 64 + k] * Ws[j * 64 + k];
        G[t] = acc;  // G[i][j]
    }
}

// ---------------------------------------------------------------------------
// k2: extractor. xh = x@We^T + be ; h0 = xh@U^T + bU ; xU = (1/nf)*h0
// (h0 == nf * xU == h at step 0 since z0 = 0)
// Wave-per-node, lane = channel. Weights transposed in LDS (conflict-free).
// ---------------------------------------------------------------------------
__global__ __launch_bounds__(256) void extractor(
        const float* __restrict__ x, const float* __restrict__ nf,
        const float* __restrict__ We, const float* __restrict__ be,
        const float* __restrict__ U,  const float* __restrict__ bU,
        float* __restrict__ xh, float* __restrict__ xU, float* __restrict__ h0) {
    __shared__ float WeT[INC * HH];   // WeT[k*64+j] = We[j][k]   (32 KB)
    __shared__ float UT[HH * HH];     // UT[k*64+j]  = U[j][k]    (16 KB)
    __shared__ float beS[HH], bUS[HH];
    __shared__ float xs[4][INC];
    __shared__ float xhs[4][HH];

    for (int t = threadIdx.x; t < INC * HH; t += 256) {
        int j = t >> 7, k = t & 127;
        WeT[k * 64 + j] = We[t];
    }
    for (int t = threadIdx.x; t < HH * HH; t += 256) {
        int j = t >> 6, k = t & 63;
        UT[k * 64 + j] = U[t];
    }
    if (threadIdx.x < 64) { beS[threadIdx.x] = be[threadIdx.x]; bUS[threadIdx.x] = bU[threadIdx.x]; }
    __syncthreads();

    int lane = threadIdx.x & 63;
    int wv   = threadIdx.x >> 6;

    for (int n0 = blockIdx.x * 4; n0 < NN; n0 += gridDim.x * 4) {
        int n = n0 + wv;
        bool valid = n < NN;
        if (valid) {
            xs[wv][lane]      = x[(size_t)n * INC + lane];
            xs[wv][lane + 64] = x[(size_t)n * INC + lane + 64];
        }
        __syncthreads();
        float acc = beS[lane];
        if (valid) {
#pragma unroll 8
            for (int k = 0; k < INC; ++k) acc += xs[wv][k] * WeT[k * 64 + lane];
            xh[n * 64 + lane] = acc;
            xhs[wv][lane] = acc;
        }
        __syncthreads();
        if (valid) {
            float acc2 = bUS[lane];
#pragma unroll 8
            for (int k = 0; k < HH; ++k) acc2 += xhs[wv][k] * UT[k * 64 + lane];
            h0[n * 64 + lane] = acc2;                 // = nf * xU
            xU[n * 64 + lane] = acc2 / nf[n];         // degree * (xh@U^T+bU)
        }
        __syncthreads();
    }
}

// ---------------------------------------------------------------------------
// k3: edge phase. One wave per edge (lane = channel).
//   d = tanh(h[r]-h[c]); m = LN(d); a[r] += m*nf[r]; a[c] -= m*nf[c]
// ---------------------------------------------------------------------------
__device__ __forceinline__ float fast_tanh(float x) {
    float ax = __builtin_fabsf(x);
    float e  = __expf(-2.0f * ax);
    float t  = (1.0f - e) / (1.0f + e);
    return __builtin_copysignf(t, x);
}

__global__ __launch_bounds__(256) void edge_phase(
        const int2* __restrict__ e32, const float* __restrict__ h,
        const float* __restrict__ nf, const float* __restrict__ gamma,
        const float* __restrict__ beta, float* __restrict__ a) {
    int lane = threadIdx.x & 63;
    float g = gamma[lane], b = beta[lane];
    int wid = blockIdx.x * (blockDim.x >> 6) + (threadIdx.x >> 6);
    int nw  = gridDim.x * (blockDim.x >> 6);
    for (int e = wid; e < EE; e += nw) {
        int2 rc = e32[e];
        float hr = h[rc.x * 64 + lane];
        float hc = h[rc.y * 64 + lane];
        float d = fast_tanh(hr - hc);
        // mean over 64 channels
        float s1 = d;
#pragma unroll
        for (int o = 32; o > 0; o >>= 1) s1 += __shfl_xor(s1, o);
        float mu = s1 * (1.0f / 64.0f);
        float dc = d - mu;
        // variance (two-pass, matches reference numerics)
        float s2 = dc * dc;
#pragma unroll
        for (int o = 32; o > 0; o >>= 1) s2 += __shfl_xor(s2, o);
        float var = s2 * (1.0f / 64.0f);
        float m = g * dc * __frsqrt_rn(var + LN_EPS) + b;
        atomicAdd(&a[rc.x * 64 + lane],  m * nf[rc.x]);
        atomicAdd(&a[rc.y * 64 + lane], -m * nf[rc.y]);
    }
}

// ---------------------------------------------------------------------------
// k4: node update.  p = a@G ; y = -alpha*p + (1-alpha)*y ;
//                   s = (1-alpha)*s + a ; h = nf*(y + xU)   (skip h on last)
// ---------------------------------------------------------------------------
__global__ __launch_bounds__(256) void node_update(
        const float* __restrict__ a, const float* __restrict__ xU,
        const float* __restrict__ nf, const float* __restrict__ Gm,
        float* __restrict__ y, float* __restrict__ s, float* __restrict__ h,
        int last) {
    __shared__ float Gs[64 * 64];   // G[k][j] at Gs[k*64+j] (conflict-free for lane=j)
    __shared__ float as[4][64];
    for (int t = threadIdx.x; t < 64 * 64; t += 256) Gs[t] = Gm[t];
    __syncthreads();
    int lane = threadIdx.x & 63, wv = threadIdx.x >> 6;
    for (int n0 = blockIdx.x * 4; n0 < NN; n0 += gridDim.x * 4) {
        int n = n0 + wv;
        float av = 0.f;
        if (n < NN) { av = a[n * 64 + lane]; as[wv][lane] = av; }
        __syncthreads();
        if (n < NN) {
            float p = 0.f;
#pragma unroll 8
            for (int k = 0; k < 64; ++k) p += as[wv][k] * Gs[k * 64 + lane];
            float yn = -ALPHA * p + (1.0f - ALPHA) * y[n * 64 + lane];
            y[n * 64 + lane] = yn;
            s[n * 64 + lane] = (1.0f - ALPHA) * s[n * 64 + lane] + av;
            if (!last) h[n * 64 + lane] = nf[n] * (yn + xU[n * 64 + lane]);
        }
        __syncthreads();
    }
}

// ---------------------------------------------------------------------------
// k5: final. z = -alpha*(s@W) ; zf = nf*z + xh ; out = zf@Wlast^T + blast
// ---------------------------------------------------------------------------
__global__ __launch_bounds__(256) void final_out(
        const float* __restrict__ s, const float* __restrict__ xh,
        const float* __restrict__ nf, const float* __restrict__ W,
        const float* __restrict__ Wlast, const float* __restrict__ blast,
        float* __restrict__ out) {
    __shared__ float Ws[64 * 64];       // W[k][j] row-major: lane=j conflict-free
    __shared__ float WlT[64 * OUTC];    // WlT[j*40+o] = Wlast[o][j]
    __shared__ float blS[OUTC];
    __shared__ float ss[4][64];
    __shared__ float zfs[4][64];
    for (int t = threadIdx.x; t < 64 * 64; t += 256) Ws[t] = W[t];
    for (int t = threadIdx.x; t < OUTC * 64; t += 256) {
        int o = t >> 6, j = t & 63;
        WlT[j * OUTC + o] = Wlast[t];
    }
    if (threadIdx.x < OUTC) blS[threadIdx.x] = blast[threadIdx.x];
    __syncthreads();
    int lane = threadIdx.x & 63, wv = threadIdx.x >> 6;
    for (int n0 = blockIdx.x * 4; n0 < NN; n0 += gridDim.x * 4) {
        int n = n0 + wv;
        if (n < NN) ss[wv][lane] = s[n * 64 + lane];
        __syncthreads();
        if (n < NN) {
            float z = 0.f;
#pragma unroll 8
            for (int k = 0; k < 64; ++k) z += ss[wv][k] * Ws[k * 64 + lane];
            z *= -ALPHA;
            zfs[wv][lane] = nf[n] * z + xh[n * 64 + lane];
        }
        __syncthreads();
        if (n < NN && lane < OUTC) {
            float acc = blS[lane];
#pragma unroll 8
            for (int j = 0; j < 64; ++j) acc += zfs[wv][j] * WlT[j * OUTC + lane];
            out[n * OUTC + lane] = acc;
        }
        __syncthreads();
    }
}

// ---------------------------------------------------------------------------
extern "C" void kernel_launch(void* const* d_in, const int* in_sizes, int n_in,
                              void* d_out, int out_size, void* d_ws, size_t ws_size,
                              hipStream_t stream) {
    const float* x     = (const float*)d_in[0];
    const int*   ei    = (const int*)  d_in[1];
    const float* nf    = (const float*)d_in[2];
    const float* We    = (const float*)d_in[3];
    const float* be    = (const float*)d_in[4];
    const float* W     = (const float*)d_in[5];
    const float* U     = (const float*)d_in[6];
    const float* bU    = (const float*)d_in[7];
    const float* gamma = (const float*)d_in[8];
    const float* beta  = (const float*)d_in[9];
    const float* Wlast = (const float*)d_in[10];
    const float* blast = (const float*)d_in[11];
    float* out = (float*)d_out;

    char* ws = (char*)d_ws;
    size_t off = 0;
    const size_t NH = (size_t)NN * HH * sizeof(float);
    int2*  e32 = (int2*)(ws + off);  off += (size_t)EE * sizeof(int2);
    float* xh  = (float*)(ws + off); off += NH;
    float* xU  = (float*)(ws + off); off += NH;
    float* h   = (float*)(ws + off); off += NH;
    float* y   = (float*)(ws + off); off += NH;
    float* s   = (float*)(ws + off); off += NH;
    float* a   = (float*)(ws + off); off += NH;
    float* G   = (float*)(ws + off); off += (size_t)HH * HH * sizeof(float);

    hipMemsetAsync(y, 0, NH, stream);
    hipMemsetAsync(s, 0, NH, stream);
    conv_edges<<<(EE + 255) / 256, 256, 0, stream>>>(ei, e32);
    make_G<<<1, 256, 0, stream>>>(W, G);
    extractor<<<512, 256, 0, stream>>>(x, nf, We, be, U, bU, xh, xU, h);

    for (int t = 0; t < 4; ++t) {
        hipMemsetAsync(a, 0, NH, stream);
        edge_phase<<<8192, 256, 0, stream>>>(e32, h, nf, gamma, beta, a);
        node_update<<<512, 256, 0, stream>>>(a, xU, nf, G, y, s, h, t == 3);
    }
    final_out<<<512, 256, 0, stream>>>(s, xh, nf, W, Wlast, blast, out);
}

// Round 2
// 3038.036 us; speedup vs baseline: 1.0178x; 1.0178x over previous
//
#include <hip/hip_runtime.h>
#include <hip/hip_bf16.h>

// Problem constants (from reference)
#define NN   50000
#define EE   1600000
#define INC  128
#define HH   64
#define OUTC 40
#define ALPHA 0.8f
#define LN_EPS 1e-5f
#define NB_SCAN 196   // ceil(NN/256)

// ---------------------------------------------------------------------------
// CSR build: incidence list. ei is [2,E] flat int32: rows [0,E), cols [E,2E).
// Incidence i: node = ei[i], other endpoint = ei[i +/- E], role = (i >= E).
// ---------------------------------------------------------------------------
__global__ __launch_bounds__(256) void csr_count(const int* __restrict__ ei,
                                                 int* __restrict__ cnt) {
    int i = blockIdx.x * 256 + threadIdx.x;
    if (i < 2 * EE) atomicAdd(&cnt[ei[i]], 1);
}

__global__ __launch_bounds__(256) void scanA(const int* __restrict__ cnt,
                                             int* __restrict__ offs,
                                             int* __restrict__ bsum) {
    __shared__ int tmp[256];
    int i = blockIdx.x * 256 + threadIdx.x;
    int v = (i < NN) ? cnt[i] : 0;
    tmp[threadIdx.x] = v;
    __syncthreads();
    int acc = v;
    for (int d = 1; d < 256; d <<= 1) {
        int t = (threadIdx.x >= d) ? tmp[threadIdx.x - d] : 0;
        __syncthreads();
        acc += t;
        tmp[threadIdx.x] = acc;
        __syncthreads();
    }
    if (i < NN) offs[i] = acc - v;                    // block-local exclusive
    if (threadIdx.x == 255) bsum[blockIdx.x] = acc;   // block total
}

__global__ void scanB(int* __restrict__ bsum) {
    if (blockIdx.x == 0 && threadIdx.x == 0) {
        int run = 0;
        for (int b = 0; b < NB_SCAN; ++b) { int v = bsum[b]; bsum[b] = run; run += v; }
    }
}

__global__ __launch_bounds__(256) void scanC(int* __restrict__ offs,
                                             const int* __restrict__ bsum) {
    int i = blockIdx.x * 256 + threadIdx.x;
    if (i < NN) offs[i] += bsum[blockIdx.x];
}

__global__ __launch_bounds__(256) void csr_fill(const int* __restrict__ ei,
                                                int* __restrict__ cur,
                                                int* __restrict__ adj) {
    int i = blockIdx.x * 256 + threadIdx.x;
    if (i >= 2 * EE) return;
    int node  = ei[i];
    int role  = (i >= EE) ? 1 : 0;
    int other = role ? ei[i - EE] : ei[i + EE];
    int p = atomicAdd(&cur[node], 1);
    adj[p] = other | (role << 31);
}

// ---------------------------------------------------------------------------
// G = W @ W^T  (64x64, symmetric). One block.
// ---------------------------------------------------------------------------
__global__ __launch_bounds__(256) void make_G(const float* __restrict__ W,
                                              float* __restrict__ G) {
    __shared__ float Ws[64 * 64];
    for (int t = threadIdx.x; t < 64 * 64; t += 256) Ws[t] = W[t];
    __syncthreads();
    for (int t = threadIdx.x; t < 64 * 64; t += 256) {
        int i = t >> 6, j = t & 63;
        float acc = 0.f;
#pragma unroll 8
        for (int k = 0; k < 64; ++k) acc += Ws[i * 64 + k] * Ws[j * 64 + k];
        G[t] = acc;
    }
}

// ---------------------------------------------------------------------------
// extractor: xh = x@We^T + be ; h0 = xh@U^T + bU (== h at step 0, z0=0) ;
//            xU = h0 / nf
// ---------------------------------------------------------------------------
__global__ __launch_bounds__(256) void extractor(
        const float* __restrict__ x, const float* __restrict__ nf,
        const float* __restrict__ We, const float* __restrict__ be,
        const float* __restrict__ U,  const float* __restrict__ bU,
        float* __restrict__ xh, float* __restrict__ xU, float* __restrict__ h0) {
    __shared__ float WeT[INC * HH];
    __shared__ float UT[HH * HH];
    __shared__ float beS[HH], bUS[HH];
    __shared__ float xs[4][INC];
    __shared__ float xhs[4][HH];

    for (int t = threadIdx.x; t < INC * HH; t += 256) {
        int j = t >> 7, k = t & 127;
        WeT[k * 64 + j] = We[t];
    }
    for (int t = threadIdx.x; t < HH * HH; t += 256) {
        int j = t >> 6, k = t & 63;
        UT[k * 64 + j] = U[t];
    }
    if (threadIdx.x < 64) { beS[threadIdx.x] = be[threadIdx.x]; bUS[threadIdx.x] = bU[threadIdx.x]; }
    __syncthreads();

    int lane = threadIdx.x & 63;
    int wv   = threadIdx.x >> 6;

    for (int n0 = blockIdx.x * 4; n0 < NN; n0 += gridDim.x * 4) {
        int n = n0 + wv;
        bool valid = n < NN;
        if (valid) {
            xs[wv][lane]      = x[(size_t)n * INC + lane];
            xs[wv][lane + 64] = x[(size_t)n * INC + lane + 64];
        }
        __syncthreads();
        float acc = beS[lane];
        if (valid) {
#pragma unroll 8
            for (int k = 0; k < INC; ++k) acc += xs[wv][k] * WeT[k * 64 + lane];
            xh[n * 64 + lane] = acc;
            xhs[wv][lane] = acc;
        }
        __syncthreads();
        if (valid) {
            float acc2 = bUS[lane];
#pragma unroll 8
            for (int k = 0; k < HH; ++k) acc2 += xhs[wv][k] * UT[k * 64 + lane];
            h0[n * 64 + lane] = acc2;
            xU[n * 64 + lane] = acc2 / nf[n];
        }
        __syncthreads();
    }
}

// ---------------------------------------------------------------------------
// fused step: per node n (one wave, lane = channel):
//   a[n]  = nf[n] * ( sum_{incidences} LN(tanh(h[n]-h[other])) - 2*beta*ncol )
//   p     = a @ G                      (G = W W^T, LDS; readlane broadcasts)
//   y     = -alpha*p + (1-alpha)*y     (y tracks z @ W^T)
//   s     = (1-alpha)*s + a            (for final z recovery)
//   h_nxt = nf*(y + xU)                (skipped on last step)
// No atomics, no inter-wave communication; h double-buffered.
// ---------------------------------------------------------------------------
__global__ __launch_bounds__(256) void fused_step(
        const int* __restrict__ adj, const int* __restrict__ offs,
        const int* __restrict__ cnt,
        const float* __restrict__ hcur, float* __restrict__ hnxt,
        const float* __restrict__ nf, const float* __restrict__ gamma,
        const float* __restrict__ beta, const float* __restrict__ Gm,
        const float* __restrict__ xU,
        float* __restrict__ y, float* __restrict__ s, int last) {
    __shared__ float Gs[64 * 64];
    for (int t = threadIdx.x; t < 64 * 64; t += 256) Gs[t] = Gm[t];
    __syncthreads();

    int lane = threadIdx.x & 63, wv = threadIdx.x >> 6;
    float g = gamma[lane], b = beta[lane];

    for (int n = blockIdx.x * 4 + wv; n < NN; n += gridDim.x * 4) {
        int base = offs[n], deg = cnt[n];
        float hn = hcur[n * 64 + lane];
        float accM = 0.f, ncol = 0.f;

        for (int c = 0; c < deg; c += 64) {
            int rem = deg - c;
            int nv  = rem < 64 ? rem : 64;
            int ev  = 0;
            if (lane < nv) ev = adj[base + c + lane];
            for (int j = 0; j < nv; ++j) {
                int e     = __shfl(ev, j);
                int other = e & 0x7fffffff;
                float ho  = hcur[other * 64 + lane];
                float xx  = hn - ho;
                float ax  = __builtin_fabsf(xx);
                float ee  = __expf(-2.0f * ax);
                float t   = (1.0f - ee) * __builtin_amdgcn_rcpf(1.0f + ee);
                float d   = __builtin_copysignf(t, xx);
                // one-pass LN stats over 64 channels
                float s1 = d, s2 = d * d;
#pragma unroll
                for (int o = 32; o > 0; o >>= 1) {
                    s1 += __shfl_xor(s1, o);
                    s2 += __shfl_xor(s2, o);
                }
                float mu  = s1 * (1.0f / 64.0f);
                float var = s2 * (1.0f / 64.0f) - mu * mu;
                var = var > 0.f ? var : 0.f;
                float m = g * (d - mu) * __frsqrt_rn(var + LN_EPS) + b;
                accM += m;
                ncol += (float)((unsigned)e >> 31);
            }
        }

        float nfn = nf[n];
        float av  = nfn * (accM - 2.0f * b * ncol);

        // p[lane] = sum_k av(lane k) * G[k][lane]  via readlane broadcast
        float p = 0.f;
        int avi = __float_as_int(av);
#pragma unroll
        for (int k = 0; k < 64; ++k) {
            float ak = __int_as_float(__builtin_amdgcn_readlane(avi, k));
            p += ak * Gs[k * 64 + lane];
        }

        float yv = -ALPHA * p + (1.0f - ALPHA) * y[n * 64 + lane];
        y[n * 64 + lane] = yv;
        s[n * 64 + lane] = (1.0f - ALPHA) * s[n * 64 + lane] + av;
        if (!last) hnxt[n * 64 + lane] = nfn * (yv + xU[n * 64 + lane]);
    }
}

// ---------------------------------------------------------------------------
// final: z = -alpha*(s@W) ; zf = nf*z + xh ; out = zf@Wlast^T + blast
// ---------------------------------------------------------------------------
__global__ __launch_bounds__(256) void final_out(
        const float* __restrict__ s, const float* __restrict__ xh,
        const float* __restrict__ nf, const float* __restrict__ W,
        const float* __restrict__ Wlast, const float* __restrict__ blast,
        float* __restrict__ out) {
    __shared__ float Ws[64 * 64];
    __shared__ float WlT[64 * OUTC];
    __shared__ float blS[OUTC];
    __shared__ float ss[4][64];
    __shared__ float zfs[4][64];
    for (int t = threadIdx.x; t < 64 * 64; t += 256) Ws[t] = W[t];
    for (int t = threadIdx.x; t < OUTC * 64; t += 256) {
        int o = t >> 6, j = t & 63;
        WlT[j * OUTC + o] = Wlast[t];
    }
    if (threadIdx.x < OUTC) blS[threadIdx.x] = blast[threadIdx.x];
    __syncthreads();
    int lane = threadIdx.x & 63, wv = threadIdx.x >> 6;
    for (int n0 = blockIdx.x * 4; n0 < NN; n0 += gridDim.x * 4) {
        int n = n0 + wv;
        if (n < NN) ss[wv][lane] = s[n * 64 + lane];
        __syncthreads();
        if (n < NN) {
            float z = 0.f;
#pragma unroll 8
            for (int k = 0; k < 64; ++k) z += ss[wv][k] * Ws[k * 64 + lane];
            z *= -ALPHA;
            zfs[wv][lane] = nf[n] * z + xh[n * 64 + lane];
        }
        __syncthreads();
        if (n < NN && lane < OUTC) {
            float acc = blS[lane];
#pragma unroll 8
            for (int j = 0; j < 64; ++j) acc += zfs[wv][j] * WlT[j * OUTC + lane];
            out[n * OUTC + lane] = acc;
        }
        __syncthreads();
    }
}

// ---------------------------------------------------------------------------
extern "C" void kernel_launch(void* const* d_in, const int* in_sizes, int n_in,
                              void* d_out, int out_size, void* d_ws, size_t ws_size,
                              hipStream_t stream) {
    const float* x     = (const float*)d_in[0];
    const int*   ei    = (const int*)  d_in[1];
    const float* nf    = (const float*)d_in[2];
    const float* We    = (const float*)d_in[3];
    const float* be    = (const float*)d_in[4];
    const float* W     = (const float*)d_in[5];
    const float* U     = (const float*)d_in[6];
    const float* bU    = (const float*)d_in[7];
    const float* gamma = (const float*)d_in[8];
    const float* beta  = (const float*)d_in[9];
    const float* Wlast = (const float*)d_in[10];
    const float* blast = (const float*)d_in[11];
    float* out = (float*)d_out;

    char* ws = (char*)d_ws;
    size_t off = 0;
    const size_t NH = (size_t)NN * HH * sizeof(float);
    int*   adj  = (int*)(ws + off);   off += (size_t)2 * EE * sizeof(int);
    int*   offs = (int*)(ws + off);   off += (size_t)NN * sizeof(int);
    int*   cnt  = (int*)(ws + off);   off += (size_t)NN * sizeof(int);
    int*   cur  = (int*)(ws + off);   off += (size_t)NN * sizeof(int);
    int*   bsum = (int*)(ws + off);   off += 256 * sizeof(int);
    float* xh   = (float*)(ws + off); off += NH;
    float* xU   = (float*)(ws + off); off += NH;
    float* h0   = (float*)(ws + off); off += NH;
    float* h1   = (float*)(ws + off); off += NH;
    float* y    = (float*)(ws + off); off += NH;
    float* s    = (float*)(ws + off); off += NH;
    float* G    = (float*)(ws + off); off += (size_t)HH * HH * sizeof(float);

    hipMemsetAsync(cnt, 0, (size_t)NN * sizeof(int), stream);
    hipMemsetAsync(y, 0, NH, stream);
    hipMemsetAsync(s, 0, NH, stream);

    // CSR build (once per launch)
    csr_count<<<(2 * EE + 255) / 256, 256, 0, stream>>>(ei, cnt);
    scanA<<<NB_SCAN, 256, 0, stream>>>(cnt, offs, bsum);
    scanB<<<1, 64, 0, stream>>>(bsum);
    scanC<<<NB_SCAN, 256, 0, stream>>>(offs, bsum);
    hipMemcpyAsync(cur, offs, (size_t)NN * sizeof(int), hipMemcpyDeviceToDevice, stream);
    csr_fill<<<(2 * EE + 255) / 256, 256, 0, stream>>>(ei, cur, adj);

    make_G<<<1, 256, 0, stream>>>(W, G);
    extractor<<<512, 256, 0, stream>>>(x, nf, We, be, U, bU, xh, xU, h0);

    float* hc = h0;
    float* hn = h1;
    for (int t = 0; t < 4; ++t) {
        fused_step<<<2048, 256, 0, stream>>>(adj, offs, cnt, hc, hn, nf, gamma,
                                             beta, G, xU, y, s, t == 3);
        float* tmp = hc; hc = hn; hn = tmp;
    }
    final_out<<<512, 256, 0, stream>>>(s, xh, nf, W, Wlast, blast, out);
}

// Round 3
// 2192.997 us; speedup vs baseline: 1.4100x; 1.3853x over previous
//
#include <hip/hip_runtime.h>
#include <hip/hip_bf16.h>

// Problem constants (from reference)
#define NN   50000
#define EE   1600000
#define INC  128
#define HH   64
#define OUTC 40
#define ALPHA 0.8f
#define LN_EPS 1e-5f
#define NB_SCAN 196   // ceil(NN/256)

// ---------------------------------------------------------------------------
// DPP wave64 sum -> total in lane 63, broadcast via readlane (VALU pipe only,
// no LDS swizzles). Canonical GCN sequence.
// ---------------------------------------------------------------------------
template <int CTRL, int MASK>
__device__ __forceinline__ float dpp_add(float v) {
    int r = __builtin_amdgcn_update_dpp(0, __float_as_int(v), CTRL, MASK, 0xf, true);
    return v + __int_as_float(r);
}
__device__ __forceinline__ float wavesum_bcast(float v) {
    v = dpp_add<0x111, 0xf>(v);   // row_shr:1
    v = dpp_add<0x112, 0xf>(v);   // row_shr:2
    v = dpp_add<0x114, 0xf>(v);   // row_shr:4
    v = dpp_add<0x118, 0xf>(v);   // row_shr:8   -> lane15 of each row = row sum
    v = dpp_add<0x142, 0xa>(v);   // row_bcast:15 rows 1,3
    v = dpp_add<0x143, 0xc>(v);   // row_bcast:31 rows 2,3 -> lane63 = total
    return __int_as_float(__builtin_amdgcn_readlane(__float_as_int(v), 63));
}

__device__ __forceinline__ float fast_tanh(float x) {
    float ax = __builtin_fabsf(x);
    float e  = __expf(-2.0f * ax);
    float t  = (1.0f - e) * __builtin_amdgcn_rcpf(1.0f + e);
    return __builtin_copysignf(t, x);
}

// ---------------------------------------------------------------------------
// CSR build: incidence list. ei is [2,E] flat int32.
// ---------------------------------------------------------------------------
__global__ __launch_bounds__(256) void csr_count(const int* __restrict__ ei,
                                                 int* __restrict__ cnt) {
    int i = blockIdx.x * 256 + threadIdx.x;
    if (i < 2 * EE) atomicAdd(&cnt[ei[i]], 1);
}

__global__ __launch_bounds__(256) void scanA(const int* __restrict__ cnt,
                                             int* __restrict__ offs,
                                             int* __restrict__ bsum) {
    __shared__ int tmp[256];
    int i = blockIdx.x * 256 + threadIdx.x;
    int v = (i < NN) ? cnt[i] : 0;
    tmp[threadIdx.x] = v;
    __syncthreads();
    int acc = v;
    for (int d = 1; d < 256; d <<= 1) {
        int t = (threadIdx.x >= d) ? tmp[threadIdx.x - d] : 0;
        __syncthreads();
        acc += t;
        tmp[threadIdx.x] = acc;
        __syncthreads();
    }
    if (i < NN) offs[i] = acc - v;                    // block-local exclusive
    if (threadIdx.x == 255) bsum[blockIdx.x] = acc;   // block total
}

// parallel exclusive scan of NB_SCAN block sums (one 256-thread block)
__global__ __launch_bounds__(256) void scanB(int* __restrict__ bsum) {
    __shared__ int tmp[256];
    int v = (threadIdx.x < NB_SCAN) ? bsum[threadIdx.x] : 0;
    tmp[threadIdx.x] = v;
    __syncthreads();
    int acc = v;
    for (int d = 1; d < 256; d <<= 1) {
        int t = (threadIdx.x >= d) ? tmp[threadIdx.x - d] : 0;
        __syncthreads();
        acc += t;
        tmp[threadIdx.x] = acc;
        __syncthreads();
    }
    if (threadIdx.x < NB_SCAN) bsum[threadIdx.x] = acc - v;  // exclusive
}

__global__ __launch_bounds__(256) void scanC(int* __restrict__ offs,
                                             int* __restrict__ cur,
                                             const int* __restrict__ bsum) {
    int i = blockIdx.x * 256 + threadIdx.x;
    if (i < NN) {
        int o = offs[i] + bsum[blockIdx.x];
        offs[i] = o;
        cur[i]  = o;
    }
}

__global__ __launch_bounds__(256) void csr_fill(const int* __restrict__ ei,
                                                int* __restrict__ cur,
                                                int* __restrict__ adj) {
    int i = blockIdx.x * 256 + threadIdx.x;
    if (i >= 2 * EE) return;
    int node  = ei[i];
    int role  = (i >= EE) ? 1 : 0;
    int other = role ? ei[i - EE] : ei[i + EE];   // node ids < 65536: fits 16 bits
    int p = atomicAdd(&cur[node], 1);
    adj[p] = other | (role << 31);
}

// ---------------------------------------------------------------------------
// G = W @ W^T  (64x64, symmetric). One block.
// ---------------------------------------------------------------------------
__global__ __launch_bounds__(256) void make_G(const float* __restrict__ W,
                                              float* __restrict__ G) {
    __shared__ float Ws[64 * 64];
    for (int t = threadIdx.x; t < 64 * 64; t += 256) Ws[t] = W[t];
    __syncthreads();
    for (int t = threadIdx.x; t < 64 * 64; t += 256) {
        int i = t >> 6, j = t & 63;
        float acc = 0.f;
#pragma unroll 8
        for (int k = 0; k < 64; ++k) acc += Ws[i * 64 + k] * Ws[j * 64 + k];
        G[t] = acc;
    }
}

// ---------------------------------------------------------------------------
// extractor: xh = x@We^T + be ; h0 = xh@U^T + bU (== h at step 0, z0=0) ;
//            xU = h0 / nf
// ---------------------------------------------------------------------------
__global__ __launch_bounds__(256) void extractor(
        const float* __restrict__ x, const float* __restrict__ nf,
        const float* __restrict__ We, const float* __restrict__ be,
        const float* __restrict__ U,  const float* __restrict__ bU,
        float* __restrict__ xh, float* __restrict__ xU, float* __restrict__ h0) {
    __shared__ float WeT[INC * HH];
    __shared__ float UT[HH * HH];
    __shared__ float beS[HH], bUS[HH];
    __shared__ float xs[4][INC];
    __shared__ float xhs[4][HH];

    for (int t = threadIdx.x; t < INC * HH; t += 256) {
        int j = t >> 7, k = t & 127;
        WeT[k * 64 + j] = We[t];
    }
    for (int t = threadIdx.x; t < HH * HH; t += 256) {
        int j = t >> 6, k = t & 63;
        UT[k * 64 + j] = U[t];
    }
    if (threadIdx.x < 64) { beS[threadIdx.x] = be[threadIdx.x]; bUS[threadIdx.x] = bU[threadIdx.x]; }
    __syncthreads();

    int lane = threadIdx.x & 63;
    int wv   = threadIdx.x >> 6;

    for (int n0 = blockIdx.x * 4; n0 < NN; n0 += gridDim.x * 4) {
        int n = n0 + wv;
        bool valid = n < NN;
        if (valid) {
            xs[wv][lane]      = x[(size_t)n * INC + lane];
            xs[wv][lane + 64] = x[(size_t)n * INC + lane + 64];
        }
        __syncthreads();
        float acc = beS[lane];
        if (valid) {
#pragma unroll 8
            for (int k = 0; k < INC; ++k) acc += xs[wv][k] * WeT[k * 64 + lane];
            xh[n * 64 + lane] = acc;
            xhs[wv][lane] = acc;
        }
        __syncthreads();
        if (valid) {
            float acc2 = bUS[lane];
#pragma unroll 8
            for (int k = 0; k < HH; ++k) acc2 += xhs[wv][k] * UT[k * 64 + lane];
            h0[n * 64 + lane] = acc2;
            xU[n * 64 + lane] = acc2 / nf[n];
        }
        __syncthreads();
    }
}

// ---------------------------------------------------------------------------
// fused step: per node n (one wave, lane = channel). LN stats via DPP
// (VALU pipe), edge broadcast via readlane (scalar), pair-wise processing
// with one-pair-ahead prefetch for load-latency hiding. No atomics.
// ---------------------------------------------------------------------------
__global__ __launch_bounds__(256) void fused_step(
        const int* __restrict__ adj, const int* __restrict__ offs,
        const int* __restrict__ cnt,
        const float* __restrict__ hcur, float* __restrict__ hnxt,
        const float* __restrict__ nf, const float* __restrict__ gamma,
        const float* __restrict__ beta, const float* __restrict__ Gm,
        const float* __restrict__ xU,
        float* __restrict__ y, float* __restrict__ s, int last) {
    __shared__ float Gs[64 * 64];
    for (int t = threadIdx.x; t < 64 * 64; t += 256) Gs[t] = Gm[t];
    __syncthreads();

    int lane = threadIdx.x & 63, wv = threadIdx.x >> 6;
    float g = gamma[lane], b = beta[lane];

    for (int n = blockIdx.x * 4 + wv; n < NN; n += gridDim.x * 4) {
        int base = offs[n], deg = cnt[n];
        float hn = hcur[n * 64 + lane];
        float accM = 0.f;
        int   ncol = 0;

        for (int c = 0; c < deg; c += 64) {
            int rem = deg - c;
            int nv  = rem < 64 ? rem : 64;
            int ev  = 0;
            if (lane < nv) ev = adj[base + c + lane];

            int jj = 0;
            if (nv >= 2) {
                int ea = __builtin_amdgcn_readlane(ev, 0);
                int eb = __builtin_amdgcn_readlane(ev, 1);
                float hoa = hcur[(ea & 0xffff) * 64 + lane];
                float hob = hcur[(eb & 0xffff) * 64 + lane];
                while (jj + 1 < nv) {
                    int j2 = jj + 2;
                    int ea_n = 0, eb_n = 0;
                    float hoa_n = 0.f, hob_n = 0.f;
                    if (j2 + 1 < nv) {                       // prefetch next pair
                        ea_n = __builtin_amdgcn_readlane(ev, j2);
                        eb_n = __builtin_amdgcn_readlane(ev, j2 + 1);
                        hoa_n = hcur[(ea_n & 0xffff) * 64 + lane];
                        hob_n = hcur[(eb_n & 0xffff) * 64 + lane];
                    }
                    float da = fast_tanh(hn - hoa);
                    float db = fast_tanh(hn - hob);
                    // two independent DPP chains -> interleave
                    float s1a = wavesum_bcast(da);
                    float s1b = wavesum_bcast(db);
                    float s2a = wavesum_bcast(da * da);
                    float s2b = wavesum_bcast(db * db);
                    float mua = s1a * 0.015625f;
                    float mub = s1b * 0.015625f;
                    float va  = s2a * 0.015625f - mua * mua;
                    float vb  = s2b * 0.015625f - mub * mub;
                    va = va > 0.f ? va : 0.f;
                    vb = vb > 0.f ? vb : 0.f;
                    float ga = g * __frsqrt_rn(va + LN_EPS);
                    float gb = g * __frsqrt_rn(vb + LN_EPS);
                    accM += ga * (da - mua) + gb * (db - mub) + 2.0f * b;
                    ncol += ((unsigned)ea >> 31) + ((unsigned)eb >> 31);
                    ea = ea_n; eb = eb_n; hoa = hoa_n; hob = hob_n;
                    jj = j2;
                }
            }
            if (jj < nv) {                                   // odd leftover
                int e = __builtin_amdgcn_readlane(ev, jj);
                float ho = hcur[(e & 0xffff) * 64 + lane];
                float d  = fast_tanh(hn - ho);
                float s1 = wavesum_bcast(d);
                float s2 = wavesum_bcast(d * d);
                float mu = s1 * 0.015625f;
                float v  = s2 * 0.015625f - mu * mu;
                v = v > 0.f ? v : 0.f;
                float gr = g * __frsqrt_rn(v + LN_EPS);
                accM += gr * (d - mu) + b;
                ncol += (unsigned)e >> 31;
            }
        }

        float nfn = nf[n];
        float av  = nfn * (accM - 2.0f * b * (float)ncol);

        // p[lane] = sum_k av(lane k) * G[k][lane]  via readlane broadcast
        float p = 0.f;
        int avi = __float_as_int(av);
#pragma unroll
        for (int k = 0; k < 64; ++k) {
            float ak = __int_as_float(__builtin_amdgcn_readlane(avi, k));
            p += ak * Gs[k * 64 + lane];
        }

        float yv = -ALPHA * p + (1.0f - ALPHA) * y[n * 64 + lane];
        y[n * 64 + lane] = yv;
        s[n * 64 + lane] = (1.0f - ALPHA) * s[n * 64 + lane] + av;
        if (!last) hnxt[n * 64 + lane] = nfn * (yv + xU[n * 64 + lane]);
    }
}

// ---------------------------------------------------------------------------
// final: z = -alpha*(s@W) ; zf = nf*z + xh ; out = zf@Wlast^T + blast
// ---------------------------------------------------------------------------
__global__ __launch_bounds__(256) void final_out(
        const float* __restrict__ s, const float* __restrict__ xh,
        const float* __restrict__ nf, const float* __restrict__ W,
        const float* __restrict__ Wlast, const float* __restrict__ blast,
        float* __restrict__ out) {
    __shared__ float Ws[64 * 64];
    __shared__ float WlT[64 * OUTC];
    __shared__ float blS[OUTC];
    __shared__ float ss[4][64];
    __shared__ float zfs[4][64];
    for (int t = threadIdx.x; t < 64 * 64; t += 256) Ws[t] = W[t];
    for (int t = threadIdx.x; t < OUTC * 64; t += 256) {
        int o = t >> 6, j = t & 63;
        WlT[j * OUTC + o] = Wlast[t];
    }
    if (threadIdx.x < OUTC) blS[threadIdx.x] = blast[threadIdx.x];
    __syncthreads();
    int lane = threadIdx.x & 63, wv = threadIdx.x >> 6;
    for (int n0 = blockIdx.x * 4; n0 < NN; n0 += gridDim.x * 4) {
        int n = n0 + wv;
        if (n < NN) ss[wv][lane] = s[n * 64 + lane];
        __syncthreads();
        if (n < NN) {
            float z = 0.f;
#pragma unroll 8
            for (int k = 0; k < 64; ++k) z += ss[wv][k] * Ws[k * 64 + lane];
            z *= -ALPHA;
            zfs[wv][lane] = nf[n] * z + xh[n * 64 + lane];
        }
        __syncthreads();
        if (n < NN && lane < OUTC) {
            float acc = blS[lane];
#pragma unroll 8
            for (int j = 0; j < 64; ++j) acc += zfs[wv][j] * WlT[j * OUTC + lane];
            out[n * OUTC + lane] = acc;
        }
        __syncthreads();
    }
}

// ---------------------------------------------------------------------------
extern "C" void kernel_launch(void* const* d_in, const int* in_sizes, int n_in,
                              void* d_out, int out_size, void* d_ws, size_t ws_size,
                              hipStream_t stream) {
    const float* x     = (const float*)d_in[0];
    const int*   ei    = (const int*)  d_in[1];
    const float* nf    = (const float*)d_in[2];
    const float* We    = (const float*)d_in[3];
    const float* be    = (const float*)d_in[4];
    const float* W     = (const float*)d_in[5];
    const float* U     = (const float*)d_in[6];
    const float* bU    = (const float*)d_in[7];
    const float* gamma = (const float*)d_in[8];
    const float* beta  = (const float*)d_in[9];
    const float* Wlast = (const float*)d_in[10];
    const float* blast = (const float*)d_in[11];
    float* out = (float*)d_out;

    char* ws = (char*)d_ws;
    size_t off = 0;
    const size_t NH = (size_t)NN * HH * sizeof(float);
    int*   adj  = (int*)(ws + off);   off += (size_t)2 * EE * sizeof(int);
    int*   offs = (int*)(ws + off);   off += (size_t)NN * sizeof(int);
    int*   cnt  = (int*)(ws + off);   off += (size_t)NN * sizeof(int);
    int*   cur  = (int*)(ws + off);   off += (size_t)NN * sizeof(int);
    int*   bsum = (int*)(ws + off);   off += 256 * sizeof(int);
    float* xh   = (float*)(ws + off); off += NH;
    float* xU   = (float*)(ws + off); off += NH;
    float* h0   = (float*)(ws + off); off += NH;
    float* h1   = (float*)(ws + off); off += NH;
    float* y    = (float*)(ws + off); off += NH;
    float* s    = (float*)(ws + off); off += NH;
    float* G    = (float*)(ws + off); off += (size_t)HH * HH * sizeof(float);

    hipMemsetAsync(cnt, 0, (size_t)NN * sizeof(int), stream);
    hipMemsetAsync(y, 0, NH, stream);
    hipMemsetAsync(s, 0, NH, stream);

    // CSR build (once per launch)
    csr_count<<<(2 * EE + 255) / 256, 256, 0, stream>>>(ei, cnt);
    scanA<<<NB_SCAN, 256, 0, stream>>>(cnt, offs, bsum);
    scanB<<<1, 256, 0, stream>>>(bsum);
    scanC<<<NB_SCAN, 256, 0, stream>>>(offs, cur, bsum);
    csr_fill<<<(2 * EE + 255) / 256, 256, 0, stream>>>(ei, cur, adj);

    make_G<<<1, 256, 0, stream>>>(W, G);
    extractor<<<512, 256, 0, stream>>>(x, nf, We, be, U, bU, xh, xU, h0);

    float* hc = h0;
    float* hn = h1;
    for (int t = 0; t < 4; ++t) {
        fused_step<<<2048, 256, 0, stream>>>(adj, offs, cnt, hc, hn, nf, gamma,
                                             beta, G, xU, y, s, t == 3);
        float* tmp = hc; hc = hn; hn = tmp;
    }
    final_out<<<512, 256, 0, stream>>>(s, xh, nf, W, Wlast, blast, out);
}